// Round 11
// baseline (438.771 us; speedup 1.0000x reference)
//
#include <hip/hip_runtime.h>
#include <hip/hip_bf16.h>
#include <hip/hip_fp16.h>
#include <string.h>

typedef __hip_bfloat16 bf16;
typedef _Float16 f16;
typedef __attribute__((ext_vector_type(8))) short short8;
typedef __attribute__((ext_vector_type(4))) float floatx4;
typedef __attribute__((ext_vector_type(4))) unsigned int uintx4;

// async global->LDS, 16B per lane; LDS dest is wave-uniform base + lane*16
#define GLD16(gp, lp) __builtin_amdgcn_global_load_lds( \
    (__attribute__((address_space(1))) void*)(gp),      \
    (__attribute__((address_space(3))) void*)(lp), 16, 0, 0)

__device__ __forceinline__ unsigned short bf16_bits(float f) {
  bf16 h = (bf16)f;
  unsigned short s;
  memcpy(&s, &h, 2);
  return s;
}
__device__ __forceinline__ __half2 u2h2(unsigned u) {
  __half2 h;
  memcpy(&h, &u, 4);
  return h;
}

// ---------------------------------------------------------------------------
// x (f32, [4][4096][1024]) -> bf16. Batch b lands at outbase + b*bstride.
// ---------------------------------------------------------------------------
__global__ __launch_bounds__(256)
void cvtx_k(const float* __restrict__ x, char* __restrict__ outbase,
            size_t bstride) {
  size_t e = ((size_t)blockIdx.x * 256 + threadIdx.x) * 8;
  int b = (int)(e >> 22);                       // 4M elements per batch
  size_t i = e & 4194303;
  const floatx4* s = (const floatx4*)(x + e);
  floatx4 a0 = s[0], a1 = s[1];
  union { uintx4 u4; unsigned short us[8]; } w;
  w.us[0] = bf16_bits(a0.x); w.us[1] = bf16_bits(a0.y);
  w.us[2] = bf16_bits(a0.z); w.us[3] = bf16_bits(a0.w);
  w.us[4] = bf16_bits(a1.x); w.us[5] = bf16_bits(a1.y);
  w.us[6] = bf16_bits(a1.z); w.us[7] = bf16_bits(a1.w);
  *(uintx4*)((bf16*)(outbase + (size_t)b * bstride) + i) = w.u4;
}

// ---------------------------------------------------------------------------
// Transpose+convert 1024x1024 f32 weights: T[n][k] = bf16(W[k][n]), 3 via z.
// ---------------------------------------------------------------------------
__global__ __launch_bounds__(256)
void transpose_k(const float* __restrict__ W0, const float* __restrict__ W1,
                 const float* __restrict__ W2, bf16* __restrict__ T0,
                 bf16* __restrict__ T1, bf16* __restrict__ T2) {
  __shared__ bf16 t[64][66];                 // +2 pad: conflict-free col reads
  const float* S = blockIdx.z == 0 ? W0 : (blockIdx.z == 1 ? W1 : W2);
  bf16* Dst      = blockIdx.z == 0 ? T0 : (blockIdx.z == 1 ? T1 : T2);
  const int tx = threadIdx.x & 63, ty = threadIdx.x >> 6;
  const int kb = blockIdx.y * 64, nb = blockIdx.x * 64;
#pragma unroll
  for (int rr = 0; rr < 16; ++rr) {
    int r = ty * 16 + rr;
    t[r][tx] = (bf16)S[(size_t)(kb + r) * 1024 + nb + tx];
  }
  __syncthreads();
#pragma unroll
  for (int rr = 0; rr < 16; ++rr) {
    int r = ty * 16 + rr;
    Dst[(size_t)(nb + r) * 1024 + kb + tx] = t[tx][r];
  }
}

// ---------------------------------------------------------------------------
// h_prep[dblk64][k][dd] = f16( h_filter[k][dblk*64+dd] * exp(-0.01k) ), k<512
// ---------------------------------------------------------------------------
__global__ __launch_bounds__(256)
void hprep_k(const float* __restrict__ hf, f16* __restrict__ hp) {
  int idx = blockIdx.x * 256 + threadIdx.x;   // < 16*512*64
  int dblk = idx >> 15;
  int rem = idx & 32767;
  int k = rem >> 6, dd = rem & 63;
  int d = dblk * 64 + dd;
  float val = hf[(size_t)k * 1024 + d] * __expf(-0.01f * (float)k);
  hp[idx] = (f16)val;
}

// ---------------------------------------------------------------------------
// 256x256 GEMM body, round-10/11: faithful 8-phase template port (m201
// family). 512 threads = 8 waves (2M x 4N), per-wave 128x64, acc[8][4].
// BK=64, 16 K-tiles, LDS 2 slots x (A 32KB + B 32KB) = 128KB.
//
// Per K-tile t (slot s=t&1), 4 phases; phase = { issue ds_reads; issue ONE
// half-tile stage (2 gld); [lgkmcnt(8) if 12 reads]; s_barrier; lgkmcnt(0)
// + sched_barrier(0); setprio(1); 16 MFMA; setprio(0); s_barrier }.
// ds_reads issued BEFORE the head barrier so their latency hides under the
// barrier wait (round-7 read after the barrier and regressed).
// Quadrants: P1 (lo,lo) reads af-lo(8)+bf-lo(4); P2 (lo,hi) reads bf-hi(4);
// P3 (hi,hi) reads af-hi(8); P4 (hi,lo) re-reads bf-lo(4).
// Stage order during t: B1(t+1)@P1 -> slot s^1; A1(t+2)@P2, B2(t+2)@P3,
// A2(t+2)@P4 -> slot s (each region's last completed read >=1 barrier-pair
// earlier -- audited hazard-free, see round-11 notes). ONE vmcnt(6) at P4
// (keep newest 3 halves -> all of tile t+1 landed). Tail: kt=14 stages only
// B1(15), vmcnt(0); kt=15 stages nothing.
// Halves: A1 = rows {0-63,128-191}, A2 = complement; B1 = rows
// {0-31,64-95,128-159,192-223}, B2 = complement.
// LDS granule permutation (rounds 4-9, conflict-free): LDS granule g of
// row R holds global k-granule g^(R&7); gld_lds dest linear, global src
// permuted: lane l -> row base+(l>>3), granule (l&7)^(l>>3).
// out_mode: 0 bf16, 1 f16, 2 f32 store.
// ---------------------------------------------------------------------------
__device__ __forceinline__
void gemm_body256(const bf16* __restrict__ A, const bf16* __restrict__ Bt,
                  const float* __restrict__ bias, void* __restrict__ Cout,
                  int out_mode, int m0, int n0) {
  constexpr int K = 1024;
  __shared__ __align__(16) bf16 Asl[2][16384];   // 2 x 32KB
  __shared__ __align__(16) bf16 Bsl[2][16384];   // 2 x 32KB
  const int tid = threadIdx.x;                   // 0..511
  const int lane = tid & 63;
  const int wave = tid >> 6;                     // 0..7
  const int wm = wave >> 2, wn = wave & 3;       // 2M x 4N
  const int r = lane & 15, qlane = lane >> 4;
  const int rx = r & 7;
  const int lrow = lane >> 3;                    // 0..7
  const int lgr = (lane & 7) ^ lrow;             // stage granule permute

  floatx4 acc[8][4] = {};

  // ---- stage geometry (per-lane physical rows for each half, 2 gld each)
  const int a1r0 = wave * 8 + lrow;              // A1: rows 0-63
  const int a1r1 = 128 + wave * 8 + lrow;        //     rows 128-191
  const int a2r0 = a1r0 + 64, a2r1 = a1r1 + 64;  // A2
  const int bL0 = wave * 8 + lrow, bL1 = 64 + wave * 8 + lrow;
  const int b1r0 = ((bL0 >> 5) << 6) + (bL0 & 31);   // B1 ranges
  const int b1r1 = ((bL1 >> 5) << 6) + (bL1 & 31);
  const int b2r0 = b1r0 + 32, b2r1 = b1r1 + 32;      // B2

  const bf16* gA1a = A + (size_t)(m0 + a1r0) * K + lgr * 8;
  const bf16* gA1b = A + (size_t)(m0 + a1r1) * K + lgr * 8;
  const bf16* gA2a = A + (size_t)(m0 + a2r0) * K + lgr * 8;
  const bf16* gA2b = A + (size_t)(m0 + a2r1) * K + lgr * 8;
  const bf16* gB1a = Bt + (size_t)(n0 + b1r0) * K + lgr * 8;
  const bf16* gB1b = Bt + (size_t)(n0 + b1r1) * K + lgr * 8;
  const bf16* gB2a = Bt + (size_t)(n0 + b2r0) * K + lgr * 8;
  const bf16* gB2b = Bt + (size_t)(n0 + b2r1) * K + lgr * 8;

  // wave-uniform LDS dest bases (bytes): contiguous 1KB per gld
  const int dA1a = (wave * 8) * 128, dA1b = (128 + wave * 8) * 128;
  const int dA2a = dA1a + 8192,      dA2b = dA1b + 8192;
  const int bb0 = ((wave * 8) >> 5) * 64 + ((wave * 8) & 31);
  const int bb1 = ((64 + wave * 8) >> 5) * 64 + ((64 + wave * 8) & 31);
  const int dB1a = bb0 * 128, dB1b = bb1 * 128;
  const int dB2a = dB1a + 4096, dB2b = dB1b + 4096;   // +32 rows

  // ---- prologue: A1,B1,B2,A2(0); A1,B2,A2(1); vmcnt(6) -> tile0 landed ----
  {
    char* A0 = (char*)&Asl[0][0];
    char* B0 = (char*)&Bsl[0][0];
    char* A1p = (char*)&Asl[1][0];
    char* B1p = (char*)&Bsl[1][0];
    GLD16(gA1a, A0 + dA1a); GLD16(gA1b, A0 + dA1b);
    GLD16(gB1a, B0 + dB1a); GLD16(gB1b, B0 + dB1b);
    GLD16(gB2a, B0 + dB2a); GLD16(gB2b, B0 + dB2b);
    GLD16(gA2a, A0 + dA2a); GLD16(gA2b, A0 + dA2b);
    GLD16(gA1a + 64, A1p + dA1a); GLD16(gA1b + 64, A1p + dA1b);
    GLD16(gB2a + 64, B1p + dB2a); GLD16(gB2b + 64, B1p + dB2b);
    GLD16(gA2a + 64, A1p + dA2a); GLD16(gA2b + 64, A1p + dA2b);
    asm volatile("s_waitcnt vmcnt(6)" ::: "memory");
    __builtin_amdgcn_s_barrier();
  }

  for (int kt = 0; kt < 16; ++kt) {
    const int s = kt & 1;
    const char* Ab = (const char*)&Asl[s][0];
    const char* Bb = (const char*)&Bsl[s][0];
    char* Ao = (char*)&Asl[s][0];        // t+2 shares slot s
    char* Bo = (char*)&Bsl[s][0];
    char* Bn = (char*)&Bsl[s ^ 1][0];    // t+1 slot (B1 only)
    const int k1 = (kt + 1) * 64, k2o = (kt + 2) * 64;
    const char* Arow = Ab + (wm * 128 + r) * 128;
    const char* Brow = Bb + (wn * 64 + r) * 128;
    const int c0 = (qlane ^ rx) * 16, c1 = ((4 + qlane) ^ rx) * 16;
    short8 af[4][2], bf[2][2];

    // ---- P1: (lo,lo); stage B1(t+1) -> slot s^1 ----
#pragma unroll
    for (int mi = 0; mi < 4; ++mi) {
      af[mi][0] = *(const short8*)(Arow + mi * 2048 + c0);
      af[mi][1] = *(const short8*)(Arow + mi * 2048 + c1);
    }
#pragma unroll
    for (int nj = 0; nj < 2; ++nj) {
      bf[nj][0] = *(const short8*)(Brow + nj * 2048 + c0);
      bf[nj][1] = *(const short8*)(Brow + nj * 2048 + c1);
    }
    if (kt < 15) {
      GLD16(gB1a + k1, Bn + dB1a);
      GLD16(gB1b + k1, Bn + dB1b);
    }
    asm volatile("s_waitcnt lgkmcnt(8)" ::: "memory");
    __builtin_amdgcn_s_barrier();
    asm volatile("s_waitcnt lgkmcnt(0)" ::: "memory");
    __builtin_amdgcn_sched_barrier(0);
    __builtin_amdgcn_s_setprio(1);
#pragma unroll
    for (int ks = 0; ks < 2; ++ks)
#pragma unroll
      for (int mi = 0; mi < 4; ++mi)
#pragma unroll
        for (int nj = 0; nj < 2; ++nj)
          acc[mi][nj] = __builtin_amdgcn_mfma_f32_16x16x32_bf16(
              af[mi][ks], bf[nj][ks], acc[mi][nj], 0, 0, 0);
    __builtin_amdgcn_s_setprio(0);
    __builtin_amdgcn_s_barrier();

    // ---- P2: (lo,hi); stage A1(t+2) -> slot s ----
#pragma unroll
    for (int nj = 0; nj < 2; ++nj) {
      bf[nj][0] = *(const short8*)(Brow + 4096 + nj * 2048 + c0);
      bf[nj][1] = *(const short8*)(Brow + 4096 + nj * 2048 + c1);
    }
    if (kt < 14) {
      GLD16(gA1a + k2o, Ao + dA1a);
      GLD16(gA1b + k2o, Ao + dA1b);
    }
    __builtin_amdgcn_s_barrier();
    asm volatile("s_waitcnt lgkmcnt(0)" ::: "memory");
    __builtin_amdgcn_sched_barrier(0);
    __builtin_amdgcn_s_setprio(1);
#pragma unroll
    for (int ks = 0; ks < 2; ++ks)
#pragma unroll
      for (int mi = 0; mi < 4; ++mi)
#pragma unroll
        for (int nj = 0; nj < 2; ++nj)
          acc[mi][2 + nj] = __builtin_amdgcn_mfma_f32_16x16x32_bf16(
              af[mi][ks], bf[nj][ks], acc[mi][2 + nj], 0, 0, 0);
    __builtin_amdgcn_s_setprio(0);
    __builtin_amdgcn_s_barrier();

    // ---- P3: (hi,hi); stage B2(t+2) -> slot s ----
#pragma unroll
    for (int mi = 0; mi < 4; ++mi) {
      af[mi][0] = *(const short8*)(Arow + 8192 + mi * 2048 + c0);
      af[mi][1] = *(const short8*)(Arow + 8192 + mi * 2048 + c1);
    }
    if (kt < 14) {
      GLD16(gB2a + k2o, Bo + dB2a);
      GLD16(gB2b + k2o, Bo + dB2b);
    }
    __builtin_amdgcn_s_barrier();
    asm volatile("s_waitcnt lgkmcnt(0)" ::: "memory");
    __builtin_amdgcn_sched_barrier(0);
    __builtin_amdgcn_s_setprio(1);
#pragma unroll
    for (int ks = 0; ks < 2; ++ks)
#pragma unroll
      for (int mi = 0; mi < 4; ++mi)
#pragma unroll
        for (int nj = 0; nj < 2; ++nj)
          acc[4 + mi][2 + nj] = __builtin_amdgcn_mfma_f32_16x16x32_bf16(
              af[mi][ks], bf[nj][ks], acc[4 + mi][2 + nj], 0, 0, 0);
    __builtin_amdgcn_s_setprio(0);
    __builtin_amdgcn_s_barrier();

    // ---- P4: (hi,lo); stage A2(t+2) -> slot s; vmcnt gate ----
#pragma unroll
    for (int nj = 0; nj < 2; ++nj) {
      bf[nj][0] = *(const short8*)(Brow + nj * 2048 + c0);
      bf[nj][1] = *(const short8*)(Brow + nj * 2048 + c1);
    }
    if (kt < 14) {
      GLD16(gA2a + k2o, Ao + dA2a);
      GLD16(gA2b + k2o, Ao + dA2b);
      asm volatile("s_waitcnt vmcnt(6)" ::: "memory");
    } else {
      asm volatile("s_waitcnt vmcnt(0)" ::: "memory");
    }
    __builtin_amdgcn_s_barrier();
    asm volatile("s_waitcnt lgkmcnt(0)" ::: "memory");
    __builtin_amdgcn_sched_barrier(0);
    __builtin_amdgcn_s_setprio(1);
#pragma unroll
    for (int ks = 0; ks < 2; ++ks)
#pragma unroll
      for (int mi = 0; mi < 4; ++mi)
#pragma unroll
        for (int nj = 0; nj < 2; ++nj)
          acc[4 + mi][nj] = __builtin_amdgcn_mfma_f32_16x16x32_bf16(
              af[mi][ks], bf[nj][ks], acc[4 + mi][nj], 0, 0, 0);
    __builtin_amdgcn_s_setprio(0);
    __builtin_amdgcn_s_barrier();
  }

  // ---- epilogue: C/D layout col(n)=lane&15, row(m)=(lane>>4)*4+reg ----
  const int cb = n0 + wn * 64;
  float bvv[4];
#pragma unroll
  for (int j = 0; j < 4; ++j) bvv[j] = bias[cb + j * 16 + r];
#pragma unroll
  for (int i = 0; i < 8; ++i) {
    int rowb = m0 + wm * 128 + i * 16 + qlane * 4;
#pragma unroll
    for (int j = 0; j < 4; ++j) {
      int col = cb + j * 16 + r;
#pragma unroll
      for (int v = 0; v < 4; ++v) {
        float val = acc[i][j][v] + bvv[j];
        size_t off = (size_t)(rowb + v) * 1024 + col;
        if (out_mode == 0)      ((bf16*)Cout)[off] = (bf16)val;
        else if (out_mode == 1) ((f16*)Cout)[off] = (f16)val;
        else                    ((float*)Cout)[off] = val;
      }
    }
  }
}

// u and v projections fused via grid.z (0: u bf16, 1: v f16).
__global__ __launch_bounds__(512, 2)
void gemm_uv_k(const bf16* __restrict__ A, const bf16* __restrict__ WuT,
               const bf16* __restrict__ WvT, const float* __restrict__ bu,
               const float* __restrict__ bv, bf16* __restrict__ u_out,
               f16* __restrict__ v_out) {
  const int isv = blockIdx.z;
  gemm_body256(A, isv ? WvT : WuT, isv ? bv : bu,
               isv ? (void*)v_out : (void*)u_out, isv,
               blockIdx.x * 256, blockIdx.y * 256);
}

// final projection: C f32
__global__ __launch_bounds__(512, 2)
void gemm_o_k(const bf16* __restrict__ A, const bf16* __restrict__ Bt,
              const float* __restrict__ bias, float* __restrict__ C) {
  gemm_body256(A, Bt, bias, (void*)C, 2, blockIdx.x * 256, blockIdx.y * 256);
}

// ---------------------------------------------------------------------------
// Truncated causal depthwise conv (T=512) + gate, packed f16x2 along d.
// Block: 64 d (32 __half2 pairs) x 128 t; thread: 1 d-pair, 16 t.
// Round-10/11 change: 2-deep hk register pipeline (hk loaded 2 k2-iterations
// before use; +2 VGPR, no LDS change, plain launch bounds -- the round-2
// pipeline test was confounded by launch_bounds-induced spills).
// LDS: vs 192x32 u32 (24KB) + hs 64x32 u32 (8KB) = 32KB.
// ---------------------------------------------------------------------------
__global__ __launch_bounds__(256)
void conv_k(const f16* __restrict__ vg0, const f16* __restrict__ hp,
            bf16* __restrict__ up0) {
  constexpr int CC = 64, TT = 128, D = 1024;
  __shared__ __align__(16) unsigned vs2[(TT + CC) * 32];  // [row][pair] 24KB
  __shared__ __align__(16) unsigned hs2[CC * 32];         // [kk][pair]   8KB
  const int tid = threadIdx.x;
  const int pp = tid & 31, tg = tid >> 5;
  const int bx = blockIdx.x;                 // d0 = bx*64
  const int t0 = blockIdx.y * TT;
  const int base = tg * 16;
  const unsigned* vg32 = (const unsigned*)(vg0 + (size_t)blockIdx.z * 4096 * D);
  unsigned* up32 = (unsigned*)(up0 + (size_t)blockIdx.z * 4096 * D);
  const uintx4* vg4 = (const uintx4*)vg32;             // 128 u4 per t-row
  const uintx4* hp4 = (const uintx4*)hp + (size_t)bx * 512 * 8;  // 8 u4/row

  float ax[16], ay[16];
#pragma unroll
  for (int i = 0; i < 16; ++i) { ax[i] = 0.f; ay[i] = 0.f; }

  for (int c = 0; c < 8; ++c) {
    const int k0 = c * CC;
    __syncthreads();   // prev chunk's reads complete before restage
    {  // stage h chunk: 64 rows x 8 u4 = 512 u4
      uintx4* hd = (uintx4*)hs2;
      hd[tid] = hp4[k0 * 8 + tid];
      hd[tid + 256] = hp4[k0 * 8 + tid + 256];
    }
    {  // stage v window rows [t0-k0-64, t0+127]: 192 x 8 u4 = 1536 u4
      uintx4* vd = (uintx4*)vs2;
#pragma unroll
      for (int it = 0; it < 6; ++it) {
        int q = it * 256 + tid;
        int row = q >> 3, dp4 = q & 7;
        int tau = t0 - k0 - CC + row;
        uintx4 val = {0, 0, 0, 0};
        if (tau >= 0) val = vg4[(size_t)tau * 128 + bx * 8 + dp4];
        vd[q] = val;
      }
    }
    __syncthreads();

    __half2 p[16];
#pragma unroll
    for (int i = 0; i < 16; ++i)
      p[i] = u2h2(vs2[(base + i + CC) * 32 + pp]);     // v[t_i - k0]
    __half2 acc2[16];
    const __half2 z2 = __float2half2_rn(0.f);
#pragma unroll
    for (int i = 0; i < 16; ++i) acc2[i] = z2;

    unsigned hb0 = hs2[pp];                 // h row 0
    unsigned hb1 = hs2[32 + pp];            // h row 1
    for (int kb = 0; kb < 4; ++kb) {
#pragma unroll
      for (int k2 = 0; k2 < 16; ++k2) {
        const int kk = kb * 16 + k2;
        __half2 hk = u2h2(hb0);             // loaded 2 iterations ago
        hb0 = hb1;
        hb1 = hs2[((kk + 2) & 63) * 32 + pp];  // wrap-reads discarded at tail
#pragma unroll
        for (int i = 0; i < 16; ++i)
          acc2[i] = __hfma2(hk, p[(i - k2) & 15], acc2[i]);
        p[(15 - k2) & 15] = u2h2(vs2[(base + CC - 1 - kk) * 32 + pp]);
      }
    }
#pragma unroll
    for (int i = 0; i < 16; ++i) {
      ax[i] += __low2float(acc2[i]);
      ay[i] += __high2float(acc2[i]);
    }
  }

  // gate: p = u * v_conv, in-place over u; one u32 = 2 bf16 per row
  const size_t rb = (size_t)(t0 + base) * 512 + bx * 32 + pp;
#pragma unroll
  for (int i = 0; i < 16; ++i) {
    unsigned uw = up32[rb + (size_t)i * 512];
    float ul = __uint_as_float((uw & 0xffffu) << 16);
    float uh = __uint_as_float(uw & 0xffff0000u);
    unsigned lo = bf16_bits(ul * ax[i]);
    unsigned hi = bf16_bits(uh * ay[i]);
    up32[rb + (size_t)i * 512] = lo | (hi << 16);
  }
}

// ---------------------------------------------------------------------------
// All inputs/outputs are FLOAT32. Internals bf16/f16.
// BIG path (ws_size >= 41 MB): full-M merged dispatches.
//   ws:   WuT 0..2MB | WvT 2..4 | WoT 4..6 | hp 6..7 | u 8..40MB (bf16)
//   d_out: xb (bf16) 0..32MB | v (f16) 32..64MB; gemm_o overwrites with f32.
// COMPACT path: per-batch loop.
// ---------------------------------------------------------------------------
extern "C" void kernel_launch(void* const* d_in, const int* in_sizes, int n_in,
                              void* d_out, int out_size, void* d_ws,
                              size_t ws_size, hipStream_t stream) {
  const float* x  = (const float*)d_in[0];
  const float* Wu = (const float*)d_in[1];
  const float* bu = (const float*)d_in[2];
  const float* Wv = (const float*)d_in[3];
  const float* bv = (const float*)d_in[4];
  const float* hf = (const float*)d_in[5];
  const float* Wo = (const float*)d_in[6];
  const float* bo = (const float*)d_in[7];
  char* ws = (char*)d_ws;
  bf16* WuT = (bf16*)(ws);
  bf16* WvT = (bf16*)(ws + 2097152);
  bf16* WoT = (bf16*)(ws + 4194304);
  f16*  hp  = (f16*)(ws + 6291456);

  dim3 tb(256);
  dim3 tg(512);
  transpose_k<<<dim3(16, 16, 3), tb, 0, stream>>>(Wu, Wv, Wo, WuT, WvT, WoT);
  hprep_k<<<dim3(2048), tb, 0, stream>>>(hf, hp);

  if (ws_size >= 42991616ull) {           // BIG: 41 MB needed
    bf16* xb = (bf16*)d_out;
    f16*  vf = (f16*)((char*)d_out + 33554432);
    bf16* u  = (bf16*)(ws + 8388608);
    cvtx_k<<<dim3(8192), tb, 0, stream>>>(x, (char*)d_out, 8388608);
    gemm_uv_k<<<dim3(64, 4, 2), tg, 0, stream>>>(xb, WuT, WvT, bu, bv, u, vf);
    conv_k<<<dim3(16, 32, 4), tb, 0, stream>>>(vf, hp, u);
    gemm_o_k<<<dim3(64, 4), tg, 0, stream>>>(u, WoT, bo, (float*)d_out);
  } else {                                // COMPACT: per-batch loop
    bf16* u_b = (bf16*)(ws + 8388608);
    cvtx_k<<<dim3(8192), tb, 0, stream>>>(x, (char*)d_out, 16777216);
    for (int b = 0; b < 4; ++b) {
      char* quarter = (char*)d_out + (size_t)b * 16777216;
      bf16* xb = (bf16*)quarter;
      f16*  vb = (f16*)(quarter + 8388608);
      float* outb = (float*)d_out + (size_t)b * 4194304;
      gemm_uv_k<<<dim3(16, 4, 2), tg, 0, stream>>>(xb, WuT, WvT, bu, bv,
                                                   u_b, vb);
      conv_k<<<dim3(16, 32, 1), tb, 0, stream>>>(vb, hp, u_b);
      gemm_o_k<<<dim3(16, 4), tg, 0, stream>>>(u_b, WoT, bo, outb);
    }
  }
}